// Round 1
// baseline (261.801 us; speedup 1.0000x reference)
//
#include <hip/hip_runtime.h>

// DETR PartMap: build [2, B, Q, H, W] outside-box masks (1.0 outside, 0.0 inside).
// B=64, Q=300, H=W=40. Output = 61.44M fp32 = 245.8 MB -> write-BW-bound.

#define B_ 64
#define Q_ 300
#define HM 40
#define WM 40

// total float4 outputs: 2*64*300*40*40 / 4 = 15,360,000
#define N4 15360000

__global__ __launch_bounds__(256) void partmap_kernel(
    const float* __restrict__ obj,
    const float* __restrict__ sub,
    const int*   __restrict__ img,   // [B,2] = (h, w) int32
    float4*      __restrict__ out)
{
    // Match numpy reference exactly: no FMA contraction (floor() boundary flips
    // cost absmax=1.0, threshold is 0.02).
    #pragma clang fp contract(off)

    int idx = blockIdx.x * 256 + threadIdx.x;     // float4 index, < N4 exactly

    // decompose: idx = ((s*64 + b)*300 + q)*40*10 + h*10 + w4
    int w4  = idx % 10;          // which float4 within the W=40 row
    int t   = idx / 10;
    int h   = t % HM;
    int sbq = t / HM;            // < 2*64*300 = 38400
    int q   = sbq % Q_;
    int sb  = sbq / Q_;          // < 128
    int b   = sb & 63;
    int s   = sb >> 6;           // 0 = object, 1 = human(sub)

    const float* coord = s ? sub : obj;
    float4 c = ((const float4*)coord)[b * Q_ + q];   // (cx, cy, w, h), 16B aligned

    float sh = (float)img[b * 2 + 0];
    float sw = (float)img[b * 2 + 1];

    // cxcywh -> xyxy, then floor(v * size / 32), fp32 ops in numpy order
    float x1f = (c.x - 0.5f * c.z) * sw / 32.0f;
    float y1f = (c.y - 0.5f * c.w) * sh / 32.0f;
    float x2f = (c.x + 0.5f * c.z) * sw / 32.0f;
    float y2f = (c.y + 0.5f * c.w) * sh / 32.0f;

    int x1 = (int)floorf(x1f);
    int y1 = (int)floorf(y1f);
    int x2 = (int)floorf(x2f);
    int y2 = (int)floorf(y2f);
    x2 = min(x2, WM - 1);
    y2 = min(y2, HM - 1);

    bool rowout = (h < y1) || (h > y2);
    int w0 = w4 * 4;

    float4 r;
    r.x = (rowout || (w0     < x1) || (w0     > x2)) ? 1.0f : 0.0f;
    r.y = (rowout || (w0 + 1 < x1) || (w0 + 1 > x2)) ? 1.0f : 0.0f;
    r.z = (rowout || (w0 + 2 < x1) || (w0 + 2 > x2)) ? 1.0f : 0.0f;
    r.w = (rowout || (w0 + 3 < x1) || (w0 + 3 > x2)) ? 1.0f : 0.0f;

    out[idx] = r;
}

extern "C" void kernel_launch(void* const* d_in, const int* in_sizes, int n_in,
                              void* d_out, int out_size, void* d_ws, size_t ws_size,
                              hipStream_t stream) {
    const float* obj = (const float*)d_in[0];   // [B,Q,4] f32
    const float* sub = (const float*)d_in[1];   // [B,Q,4] f32
    const int*   img = (const int*)d_in[2];     // [B,2] int32 (h, w)
    // d_in[3] = mask (bool) — only its shape is used; ignored.

    float4* out = (float4*)d_out;               // [2,B,Q,H,W] f32

    dim3 grid(N4 / 256);                        // 60,000 blocks
    dim3 block(256);
    partmap_kernel<<<grid, block, 0, stream>>>(obj, sub, img, out);
}

// Round 2
// 235.074 us; speedup vs baseline: 1.1137x; 1.1137x over previous
//
#include <hip/hip_runtime.h>
#include <stdint.h>

// DETR PartMap: [2, B, Q, H, W] outside-box masks (1.0 outside, 0.0 inside).
// B=64, Q=300, H=W=40. Output 61.44M fp32 = 245.8 MB -> write-BW-bound.
//
// Two-phase: kernel1 computes each (s,b,q) box ONCE (38,400 boxes), packing
// a 40-bit x-outside bitmask + y1/y2 (int8) into 8 bytes in d_ws. kernel2
// streams the 245.8 MB output with ~30 VALU insts per float4 (vs ~70 when
// recomputing the box per thread, which measured ~2.1 TB/s VALU-bound).

#define B_ 64
#define Q_ 300
#define HM 40
#define WM 40
#define NBOX (2 * B_ * Q_)        // 38,400
#define N4   15360000             // 2*64*300*40*40 / 4

__global__ __launch_bounds__(256) void box_prep_kernel(
    const float* __restrict__ obj,
    const float* __restrict__ sub,
    const int*   __restrict__ img,     // [B,2] = (h, w) int32
    uint32_t*    __restrict__ tbl)     // [NBOX][2]: {xmask_lo, xmask_hi|y1<<8|y2<<16}
{
    #pragma clang fp contract(off)
    int id = blockIdx.x * 256 + threadIdx.x;
    if (id >= NBOX) return;

    // id = (s*64 + b)*300 + q
    int q  = id % Q_;
    int sb = id / Q_;
    int b  = sb & 63;
    int s  = sb >> 6;

    const float* coord = s ? sub : obj;
    float4 c = ((const float4*)coord)[b * Q_ + q];   // (cx, cy, w, h)

    float sh = (float)img[b * 2 + 0];
    float sw = (float)img[b * 2 + 1];

    // Exact numpy op order: (cx - 0.5*w) * sw / 32, floor, cast. No contraction.
    float x1f = (c.x - 0.5f * c.z) * sw / 32.0f;
    float y1f = (c.y - 0.5f * c.w) * sh / 32.0f;
    float x2f = (c.x + 0.5f * c.z) * sw / 32.0f;
    float y2f = (c.y + 0.5f * c.w) * sh / 32.0f;

    int x1 = (int)floorf(x1f);            // can be negative (>= -20)
    int y1 = (int)floorf(y1f);
    int x2 = min((int)floorf(x2f), WM - 1);   // in [0,39]
    int y2 = min((int)floorf(y2f), HM - 1);   // in [0,39]

    // inside-x bits [x1 .. x2] within 40 bits; outside = complement.
    uint64_t lo = (x1 <= 0) ? ~0ull : ~((1ull << x1) - 1ull);   // x1 <= 39
    uint64_t hi = (1ull << (x2 + 1)) - 1ull;                    // x2 in [0,39]
    uint64_t outside = (~(lo & hi)) & ((1ull << 40) - 1ull);

    uint32_t d0 = (uint32_t)outside;
    uint32_t d1 = ((uint32_t)(outside >> 32) & 0xFFu)
                | (((uint32_t)y1 & 0xFFu) << 8)
                | (((uint32_t)y2 & 0xFFu) << 16);

    tbl[id * 2 + 0] = d0;
    tbl[id * 2 + 1] = d1;
}

__global__ __launch_bounds__(256) void partmap_stream_kernel(
    const uint32_t* __restrict__ tbl,
    float4*         __restrict__ out)
{
    int idx = blockIdx.x * 256 + threadIdx.x;   // float4 index, < N4 exactly

    // idx = sbq*400 + h*10 + w4
    int sbq = idx / 400;
    int rem = idx - sbq * 400;
    int h   = rem / 10;
    int w4  = rem - h * 10;

    // 400 consecutive threads share one table entry -> L1 broadcast.
    uint32_t d0 = tbl[sbq * 2 + 0];
    uint32_t d1 = tbl[sbq * 2 + 1];

    int y1 = (int)(int8_t)(d1 >> 8);
    int y2 = (int)(int8_t)(d1 >> 16);

    // all-ones if h outside [y1,y2]: sign bit of (h-y1)|(y2-h)
    int rneg = ((h - y1) | (y2 - h)) >> 31;

    // funnel-shift the 40-bit x-outside mask down by w0=4*w4; bits 0..3 are
    // the 4 elements of this float4 (y1/y2 bytes in d1 land at bits >= 4).
    int w0 = w4 * 4;
    uint32_t shifted = (uint32_t)((((uint64_t)d1 << 32) | d0) >> w0);
    uint32_t m = shifted | (uint32_t)rneg;

    float4 r;
    r.x = (float)( m        & 1u);
    r.y = (float)((m >> 1)  & 1u);
    r.z = (float)((m >> 2)  & 1u);
    r.w = (float)((m >> 3)  & 1u);

    out[idx] = r;
}

extern "C" void kernel_launch(void* const* d_in, const int* in_sizes, int n_in,
                              void* d_out, int out_size, void* d_ws, size_t ws_size,
                              hipStream_t stream) {
    const float* obj = (const float*)d_in[0];   // [B,Q,4] f32
    const float* sub = (const float*)d_in[1];   // [B,Q,4] f32
    const int*   img = (const int*)d_in[2];     // [B,2] int32 (h, w)
    // d_in[3] = mask (bool) — only its shape is used; ignored.

    uint32_t* tbl = (uint32_t*)d_ws;            // 38,400 * 8 B = 307 KB
    float4*   out = (float4*)d_out;

    box_prep_kernel<<<dim3((NBOX + 255) / 256), dim3(256), 0, stream>>>(obj, sub, img, tbl);
    partmap_stream_kernel<<<dim3(N4 / 256), dim3(256), 0, stream>>>(tbl, out);
}